// Round 6
// baseline (179.116 us; speedup 1.0000x reference)
//
#include <hip/hip_runtime.h>

typedef unsigned short u16;
typedef __attribute__((ext_vector_type(8))) short short8;   // 8 bf16 (4 VGPRs) MFMA A/B frag
typedef __attribute__((ext_vector_type(4))) short shortx4;  // 4 bf16 (8B)
typedef __attribute__((ext_vector_type(4))) float floatx4;  // MFMA C/D frag

#define S_ 2048
#define D_ 1024
#define DQKV_ 3072
#define H_ 16
#define DH_ 64

#define EXP2F(x) __builtin_amdgcn_exp2f(x)

template <bool B> struct BoolC { static constexpr bool value = B; };

__device__ __forceinline__ float bf2f(u16 x) {
    union { unsigned int u; float f; } v; v.u = ((unsigned int)x) << 16; return v.f;
}
__device__ __forceinline__ u16 f2bf(float f) {  // RNE
    unsigned int u = __float_as_uint(f);
    return (u16)((u + 0x7fffu + ((u >> 16) & 1u)) >> 16);
}
// pack 2 f32 -> 2 bf16 in one u32 (D.lo = lo, D.hi = hi); no builtin on gfx950
__device__ __forceinline__ unsigned int cvtpk_bf16(float lo, float hi) {
    unsigned int r;
    asm("v_cvt_pk_bf16_f32 %0, %1, %2" : "=v"(r) : "v"(lo), "v"(hi));
    return r;
}

// async global->LDS, 16B per lane; LDS dest is wave-uniform base + lane*16 (m97/m104)
__device__ __forceinline__ void async16(const void* g, void* l) {
    __builtin_amdgcn_global_load_lds(
        (const __attribute__((address_space(1))) unsigned int*)g,
        (__attribute__((address_space(3))) unsigned int*)l, 16, 0, 0);
}

// ---- prep: fused convert_x (z=4..7) + W transposes (z=0..3). One launch, was two. ----
// Launch-gap theory (R6): ~10us serialization per kernel; merging cuts one gap.
__global__ __launch_bounds__(256) void prep(const float* __restrict__ x,
                                            const float* __restrict__ Wq, const float* __restrict__ Wk,
                                            const float* __restrict__ Wv, const float* __restrict__ Wo,
                                            u16* __restrict__ xb, u16* __restrict__ Wqkvt, u16* __restrict__ Wot) {
    __shared__ u16 tile[32][33];
    const int z = blockIdx.z;
    const int tx = threadIdx.x, ty = threadIdx.y;
    if (z >= 4) {  // convert_x path: slice (z-4), 1024 blocks x 256 thr x 4 floats
        const int t = ty * 32 + tx;
        const size_t bid = (size_t)(z - 4) * 1024 + blockIdx.y * 32 + blockIdx.x;
        const size_t i = (bid * 256 + t) * 4;
        float4 v = *(const float4*)&x[i];
        shortx4 h;
        h[0] = (short)f2bf(v.x); h[1] = (short)f2bf(v.y);
        h[2] = (short)f2bf(v.z); h[3] = (short)f2bf(v.w);
        *(shortx4*)&xb[i] = h;
        return;
    }
    const float* W = (z == 0) ? Wq : (z == 1) ? Wk : (z == 2) ? Wv : Wo;
    u16* dst = (z == 3) ? Wot : (Wqkvt + (size_t)z * D_ * D_);
    const int n0 = blockIdx.x * 32, k0 = blockIdx.y * 32;
#pragma unroll
    for (int r = 0; r < 4; ++r) {
        int k = ty + r * 8;
        tile[k][tx] = f2bf(W[(size_t)(k0 + k) * D_ + n0 + tx]);
    }
    __syncthreads();
#pragma unroll
    for (int r = 0; r < 4; ++r) {
        int n = ty + r * 8;
        dst[(size_t)(n0 + n) * D_ + k0 + tx] = tile[tx][n];
    }
}

// ------- C[M,N] = A[M,K] @ Bt[N,K]^T + bias; bf16 in, fp32 acc -------
// BMxBN tile, BK=32. Async-DMA DOUBLE-buffered, ONE barrier per K-iter:
// barrier's implicit vmcnt(0) drains the DMA issued one full iteration earlier;
// prefetch for k+1 overlaps MFMA on k. 4 waves in 2x2 grid.
// Kept from R3: bijective XCD swizzle (T1); bf16 output staged through LDS then
// written as coalesced dwordx4 (kills write-RMW).
// R6: V-column tiles (n0>=2048) write DIRECTLY into Vt[bh][d][s] with the sigma
// key-permutation baked in (transposed LDS staging via sigma_inv; lane's 4 acc
// values stay contiguous -> b64 writes, <=2-way banked; readout = row-contiguous
// b128 + coalesced 16B global stores). Replaces the whole transpose_headV kernel;
// V cols are never written to QKV (-8MB HBM writes, -16MB transpose traffic, -1 launch).
// sigma(p) = 32p5+16p2+4(p4p3)+(p1p0);  sigma_inv(s) = 32s5+16s3+8s2+4s4+2s1+s0.
// Consumer (attn) semantics unchanged: Vt[bh][d][s0+p] = V[key s0+sigma(p)][d].
template <int BM, int BN, bool OUTF32>
__global__ __launch_bounds__(256) void gemm_bt(const u16* __restrict__ A, const u16* __restrict__ Bt,
                                               const float* __restrict__ b0, const float* __restrict__ b1,
                                               const float* __restrict__ b2, void* __restrict__ Cp,
                                               u16* __restrict__ Vt, int M, int N, int Kd) {
    constexpr int FI = BM / 32, FJ = BN / 32;
    __shared__ __align__(16) u16 smem[2][(BM + BN) * 32];  // [buf][A-tile | B-tile]
    const int t = threadIdx.x;

    // XCD-aware bijective swizzle (nwg % 8 == 0 for both launches: 768, 512)
    const int nwg = gridDim.x * gridDim.y;
    int fid = blockIdx.y * gridDim.x + blockIdx.x;
    if ((nwg & 7) == 0) fid = (fid & 7) * (nwg >> 3) + (fid >> 3);
    const int bx = fid % gridDim.x, by = fid / gridDim.x;
    const int m0 = by * BM, n0 = bx * BN;

    const int w = t >> 6, lane = t & 63;
    const int lr = lane & 15, lg = lane >> 4;
    const int wm = (w >> 1) * (BM / 2), wn = (w & 1) * (BN / 2);
    const int srow = lane >> 2, scol = (lane & 3) << 3;  // lane -> (row-in-16, k8)
    floatx4 acc[FI][FJ] = {};

    auto stage = [&](int buf, int k0) {
        u16* As = &smem[buf][0];
        u16* Bs = &smem[buf][BM * 32];
#pragma unroll
        for (int c = 0; c < BM / 64; ++c) {  // one wave-inst stages 16 rows x 64B = 1KB
            int rbase = (w * (BM / 64) + c) * 16;
            async16(&A[(size_t)(m0 + rbase + srow) * Kd + k0 + scol], &As[rbase * 32]);
        }
#pragma unroll
        for (int c = 0; c < BN / 64; ++c) {
            int rbase = (w * (BN / 64) + c) * 16;
            async16(&Bt[(size_t)(n0 + rbase + srow) * Kd + k0 + scol], &Bs[rbase * 32]);
        }
    };

    stage(0, 0);  // prologue
    const int nk = Kd / 32;
    for (int kk = 0; kk < nk; ++kk) {
        const int cur = kk & 1;
        __syncthreads();  // drains vmcnt(0): buffer `cur` ready; all waves done with cur^1
        if (kk + 1 < nk) stage(cur ^ 1, (kk + 1) * 32);
        const u16* As = &smem[cur][0];
        const u16* Bs = &smem[cur][BM * 32];

        short8 af[FI], bfr[FJ];
#pragma unroll
        for (int i = 0; i < FI; ++i) af[i]  = *(const short8*)&As[(wm + i * 16 + lr) * 32 + lg * 8];
#pragma unroll
        for (int j = 0; j < FJ; ++j) bfr[j] = *(const short8*)&Bs[(wn + j * 16 + lr) * 32 + lg * 8];
#pragma unroll
        for (int i = 0; i < FI; ++i)
#pragma unroll
            for (int j = 0; j < FJ; ++j)
                acc[i][j] = __builtin_amdgcn_mfma_f32_16x16x32_bf16(af[i], bfr[j], acc[i][j], 0, 0, 0);
    }

    if (!OUTF32) {
        __syncthreads();  // all frag reads done; smem reusable as C-staging
        u16* Cs = &smem[0][0];
        if (BM == BN && n0 >= 2048) {
            // ---- fused V epilogue: transposed + sigma_inv staging, write Vt ----
            const int bb = m0 >> 11;        // batch
            const int s_in = m0 & 2047;     // s-offset within batch
            const int h0 = (n0 - 2048) >> 6;
#pragma unroll
            for (int j = 0; j < FJ; ++j) {
                int c = wn + j * 16 + lr;                 // local d-col (0..127)
                float bv = b2[(n0 + c) & 1023];           // V bias = h*64+d
#pragma unroll
                for (int i = 0; i < FI; ++i) {
                    int r = wm + i * 16 + lg * 4;         // local s-row (mult of 4)
                    int s6 = r & 63;
                    int P = (r & ~63) | (s6 & 32) | (((s6 >> 3) & 1) << 4) | (((s6 >> 2) & 1) << 3)
                          | (((s6 >> 4) & 1) << 2);       // sigma_inv, low2 bits = 0
                    shortx4 pk4;
#pragma unroll
                    for (int ii = 0; ii < 4; ++ii) pk4[ii] = (short)f2bf(acc[i][j][ii] + bv);
                    // Cs_t[c][P^swz]: b64 write, XOR keeps 8B alignment (bits 3..6)
                    *(shortx4*)&Cs[c * BM + (P ^ ((c & 15) << 3))] = pk4;
                }
            }
            __syncthreads();
#pragma unroll
            for (int it = 0; it < (BM * BN / 8) / 256; ++it) {
                int ch = t & 15;                 // 16B chunk along s
                int dl = it * 16 + (t >> 4);     // local d-col
                short8 vv = *(const short8*)&Cs[dl * BM + ((ch * 8) ^ ((dl & 15) << 3))];
                int hh = h0 + (dl >> 6), d = dl & 63;
                *(short8*)&Vt[((size_t)((bb * 16 + hh) * 64 + d)) * (size_t)S_ + s_in + ch * 8] = vv;
            }
        } else {
            // --- LDS-staged coalesced bf16 epilogue (Q/K tiles) ---
#pragma unroll
            for (int j = 0; j < FJ; ++j) {
                int c = wn + j * 16 + lr;
                int col = n0 + c;
                const float* bp = (col < 1024) ? b0 : (col < 2048) ? b1 : b2;
                float bv = bp[col & 1023];
#pragma unroll
                for (int i = 0; i < FI; ++i)
#pragma unroll
                    for (int ii = 0; ii < 4; ++ii) {
                        int r = wm + i * 16 + lg * 4 + ii;
                        Cs[r * BN + (c ^ ((r & 15) << 3))] = f2bf(acc[i][j][ii] + bv);
                    }
            }
            __syncthreads();
            constexpr int CPR = BN / 8;               // 16B chunks per row
            constexpr int ITER = BM * CPR / 256;      // chunks per thread
#pragma unroll
            for (int it = 0; it < ITER; ++it) {
                int g = it * 256 + t;
                int r = g / CPR, cc = g % CPR;
                short8 vv = *(const short8*)&Cs[r * BN + ((cc * 8) ^ ((r & 15) << 3))];
                *(short8*)((u16*)Cp + (size_t)(m0 + r) * N + n0 + cc * 8) = vv;
            }
        }
    } else {
        // fp32 path: 16 lanes x 4B = 64B per row-group, already full-sector coalesced
#pragma unroll
        for (int j = 0; j < FJ; ++j) {
            int col = n0 + wn + j * 16 + lr;
            const float* bp = (col < 1024) ? b0 : (col < 2048) ? b1 : b2;
            float bv = bp[col & 1023];
#pragma unroll
            for (int i = 0; i < FI; ++i) {
                int rb = m0 + wm + i * 16 + lg * 4;
#pragma unroll
                for (int ii = 0; ii < 4; ++ii)
                    ((float*)Cp)[(size_t)(rb + ii) * N + col] = acc[i][j][ii] + bv;
            }
        }
    }
}

// ---------------- MFMA flash attention: swapped-QK^T, P in-register, split-KQ waves ----------------
// grid (bh=32, y=32). 256-thr blocks. Waves split 2x2 over (q-half wq, key-half wk);
// K/V staging, XOR swizzle, sigma-permuted V, in-register P (verified R3/R5 paths).
// Two key-halves merge once at the end via 16KB LDS reduction. Balanced qt remap.
__global__ __launch_bounds__(256, 4) void attn_mfma(const u16* __restrict__ QKV, const u16* __restrict__ Vt,
                                                    u16* __restrict__ O) {
    __shared__ __align__(16) u16 KsA[2][64 * 64];  // [key][d], packed 128B rows, XOR-swizzled chunks
    __shared__ __align__(16) u16 VsA[2][64 * 64];  // [d][key-permuted]
    const int t = threadIdx.x, w = t >> 6, lane = t & 63;
    const int lr = lane & 15, lg = lane >> 4;
    const int wq = w & 1, wk = w >> 1;
    const int bh = blockIdx.x, b = bh >> 4, h = bh & 15;
    const int ya = blockIdx.y & 7, yb = blockIdx.y >> 3;
    const int a4 = (ya + 4) & 7;
    const int cq = (yb == 0) ? ya : (yb == 1) ? (7 - ya) : (yb == 2) ? a4 : (7 - a4);
    const int qt = (yb << 3) + cq;
    const int q0 = qt << 6;
    const float cs = 0.18033688f;  // (1/sqrt(64)) * log2(e)

    const u16* Kb  = QKV + (size_t)b * S_ * DQKV_ + 1024 + h * DH_;  // row stride DQKV_
    const u16* Vtb = Vt + (size_t)bh * DH_ * S_;                     // row stride S_

    const int rb8 = lane >> 3;               // row within 8-row staging group
    const int cc = ((lane & 7) ^ rb8) << 3;  // swizzled source chunk (u16 offset)
    const int swz = lr & 7;                  // frag-read swizzle key (= row&7)

    short8 qf[2][2];  // Q frags (B-operand): [qs][ks] rows q0+wq*32+qs*16+lr, d-chunk ks*32+lg*8
#pragma unroll
    for (int qs = 0; qs < 2; ++qs)
#pragma unroll
        for (int ks = 0; ks < 2; ++ks)
            qf[qs][ks] = *(const short8*)&QKV[(size_t)(b * S_ + q0 + wq * 32 + qs * 16 + lr) * DQKV_ +
                                              h * DH_ + ks * 32 + lg * 8];

    floatx4 of[2][4] = {};   // O-partial [qs][ttd]: row(q16)=lg*4+ii, col(d)=ttd*16+lr
    float lsum[2] = {0.f, 0.f};  // per-lane row-sum partial, per q-subblock

    auto stage = [&](int buf, int kbase) {
        u16* Kd = &KsA[buf][w * 512];  // wave w stages rows w*8.. and 32+w*8.. (K and V)
        u16* Vd = &VsA[buf][w * 512];
        async16(&Kb[(size_t)(kbase + w * 8 + rb8) * DQKV_ + cc], Kd);
        async16(&Kb[(size_t)(kbase + 32 + w * 8 + rb8) * DQKV_ + cc], Kd + 2048);
        async16(&Vtb[(size_t)(w * 8 + rb8) * S_ + kbase + cc], Vd);
        async16(&Vtb[(size_t)(32 + w * 8 + rb8) * S_ + kbase + cc], Vd + 2048);
    };

    stage(0, 0);  // prologue: DMA tile 0 into buffer 0

    auto body = [&](int kb, auto diagc) {
        constexpr bool DIAG = decltype(diagc)::value;
        const int cur = kb & 1;
        __syncthreads();  // implicit vmcnt(0) drain: buffer `cur` is ready
        if (kb < qt) stage(cur ^ 1, (kb + 1) << 6);  // prefetch overlaps compute below
        const u16* Kc = KsA[cur];
        const u16* Vc = VsA[cur];

        // S^T = K @ Q^T on this wave's quadrant: sf[qs][tt]
        floatx4 sf[2][2] = {};
        __builtin_amdgcn_s_setprio(1);
#pragma unroll
        for (int ks = 0; ks < 2; ++ks)
#pragma unroll
            for (int tt = 0; tt < 2; ++tt) {
                short8 kf = *(const short8*)&Kc[(wk * 32 + tt * 16 + lr) * 64 + ((((ks << 2) + lg) ^ swz) << 3)];
                sf[0][tt] = __builtin_amdgcn_mfma_f32_16x16x32_bf16(kf, qf[0][ks], sf[0][tt], 0, 0, 0);
                sf[1][tt] = __builtin_amdgcn_mfma_f32_16x16x32_bf16(kf, qf[1][ks], sf[1][tt], 0, 0, 0);
            }
        __builtin_amdgcn_s_setprio(0);

        // no-max softmax, per-lane: e = 2^(s*cs); masked -> 0 (diag tile only)
        float ev[2][2][4];
#pragma unroll
        for (int qs = 0; qs < 2; ++qs)
#pragma unroll
            for (int tt = 0; tt < 2; ++tt) {
                float s0;
#pragma unroll
                for (int ii = 0; ii < 4; ++ii) {
                    float e = EXP2F(sf[qs][tt][ii] * cs);
                    if (DIAG && (wk * 32 + tt * 16 + lg * 4 + ii > wq * 32 + qs * 16 + lr)) e = 0.f;
                    ev[qs][tt][ii] = e;
                    s0 = (ii == 0) ? e : s0 + e;
                }
                lsum[qs] += s0;
            }

        // PV partial (positions ks=wk only): A = lane's own e's (sigma alignment),
        // B = V rows, chunk (wk,lg).
        short8 vfr[4];
#pragma unroll
        for (int ttd = 0; ttd < 4; ++ttd)
            vfr[ttd] = *(const short8*)&Vc[(ttd * 16 + lr) * 64 + ((((wk << 2) + lg) ^ swz) << 3)];
        __builtin_amdgcn_s_setprio(1);
#pragma unroll
        for (int qs = 0; qs < 2; ++qs) {
            union { short8 s; unsigned int u[4]; } pk;
            pk.u[0] = cvtpk_bf16(ev[qs][0][0], ev[qs][0][1]);
            pk.u[1] = cvtpk_bf16(ev[qs][0][2], ev[qs][0][3]);
            pk.u[2] = cvtpk_bf16(ev[qs][1][0], ev[qs][1][1]);
            pk.u[3] = cvtpk_bf16(ev[qs][1][2], ev[qs][1][3]);
#pragma unroll
            for (int ttd = 0; ttd < 4; ++ttd)
                of[qs][ttd] = __builtin_amdgcn_mfma_f32_16x16x32_bf16(pk.s, vfr[ttd], of[qs][ttd], 0, 0, 0);
        }
        __builtin_amdgcn_s_setprio(0);
    };

    for (int kb = 0; kb < qt; ++kb) body(kb, BoolC<false>{});  // full tiles: no mask code
    body(qt, BoolC<true>{});                                   // diagonal tile: masked

    // ---- merge the two key-halves (once): wk=1 waves publish, wk=0 waves reduce ----
    __syncthreads();  // all waves done with K/V LDS; reuse as merge buffers
    float* mb = (float*)&KsA[0][0];
    float* lb = (float*)&VsA[0][0];
    if (wk == 1) {
        float* mw = mb + wq * 2048;
#pragma unroll
        for (int qs = 0; qs < 2; ++qs)
#pragma unroll
            for (int ttd = 0; ttd < 4; ++ttd)
                *(floatx4*)&mw[(qs * 4 + ttd) * 256 + lane * 4] = of[qs][ttd];
        lb[wq * 128 + lane * 2 + 0] = lsum[0];
        lb[wq * 128 + lane * 2 + 1] = lsum[1];
    }
    __syncthreads();
    if (wk == 0) {
        float* mw = mb + wq * 2048;
#pragma unroll
        for (int qs = 0; qs < 2; ++qs)
#pragma unroll
            for (int ttd = 0; ttd < 4; ++ttd)
                of[qs][ttd] += *(const floatx4*)&mw[(qs * 4 + ttd) * 256 + lane * 4];
        lsum[0] += lb[wq * 128 + lane * 2 + 0];
        lsum[1] += lb[wq * 128 + lane * 2 + 1];

        float rv[2][4];
#pragma unroll
        for (int qs = 0; qs < 2; ++qs) {
            float s = lsum[qs];
            s += __shfl_xor(s, 16);
            s += __shfl_xor(s, 32);
            float rinv = 1.f / s;
#pragma unroll
            for (int ii = 0; ii < 4; ++ii)
                rv[qs][ii] = __shfl(rinv, (lane & 48) | (lg * 4 + ii));
        }
#pragma unroll
        for (int qs = 0; qs < 2; ++qs)
#pragma unroll
            for (int ttd = 0; ttd < 4; ++ttd)
#pragma unroll
                for (int ii = 0; ii < 4; ++ii)
                    O[(size_t)(b * S_ + q0 + wq * 32 + qs * 16 + lg * 4 + ii) * D_ + h * DH_ + ttd * 16 + lr] =
                        f2bf(of[qs][ttd][ii] * rv[qs][ii]);
    }
}

extern "C" void kernel_launch(void* const* d_in, const int* in_sizes, int n_in,
                              void* d_out, int out_size, void* d_ws, size_t ws_size,
                              hipStream_t stream) {
    (void)in_sizes; (void)n_in; (void)out_size; (void)ws_size;
    const float* x  = (const float*)d_in[0];
    const float* Wq = (const float*)d_in[1];
    const float* bq = (const float*)d_in[2];
    const float* Wk = (const float*)d_in[3];
    const float* bk = (const float*)d_in[4];
    const float* Wv = (const float*)d_in[5];
    const float* bv = (const float*)d_in[6];
    const float* Wo = (const float*)d_in[7];
    const float* bo = (const float*)d_in[8];

    // ws layout (u16 elems), 48 MB total:
    //   [0,3M) WqkvT  [3M,4M) WoT  [4M,16M) QKV  [16M,20M) Vt  [20M,24M) xbf -> reused as Am
    u16* ws    = (u16*)d_ws;
    u16* WqkvT = ws;
    u16* WoT   = ws + (size_t)3 * (1 << 20);
    u16* QKV   = ws + (size_t)4 * (1 << 20);
    u16* Vtm   = ws + (size_t)16 * (1 << 20);
    u16* xbf   = ws + (size_t)20 * (1 << 20);
    u16* Am    = ws + (size_t)20 * (1 << 20);

    // fused convert + W transposes (1 launch, was 2)
    prep<<<dim3(32, 32, 8), dim3(32, 8), 0, stream>>>(x, Wq, Wk, Wv, Wo, xbf, WqkvT, WoT);

    // QKV = xbf @ WqkvT^T + [bq|bk|bv]  (M=4096, N=3072); V-cols go straight to Vt
    // with sigma baked in (fused transpose_headV, 1 fewer launch)
    gemm_bt<128, 128, false><<<dim3(DQKV_ / 128, 4096 / 128), 256, 0, stream>>>(
        xbf, WqkvT, bq, bk, bv, QKV, Vtm, 4096, DQKV_, 1024);

    attn_mfma<<<dim3(32, 32), 256, 0, stream>>>(QKV, Vtm, Am);

    // out = Am @ WoT^T + bo  (M=4096, N=1024), fp32 out
    gemm_bt<64, 128, true><<<dim3(1024 / 128, 4096 / 64), 256, 0, stream>>>(
        Am, WoT, bo, bo, bo, d_out, nullptr, 4096, 1024, 1024);
}

// Round 9
// 177.086 us; speedup vs baseline: 1.0115x; 1.0115x over previous
//
#include <hip/hip_runtime.h>

typedef unsigned short u16;
typedef __attribute__((ext_vector_type(8))) short short8;   // 8 bf16 (4 VGPRs) MFMA A/B frag
typedef __attribute__((ext_vector_type(4))) short shortx4;  // 4 bf16 (8B)
typedef __attribute__((ext_vector_type(4))) float floatx4;  // MFMA C/D frag

#define S_ 2048
#define D_ 1024
#define DQKV_ 3072
#define H_ 16
#define DH_ 64

#define EXP2F(x) __builtin_amdgcn_exp2f(x)

template <bool B> struct BoolC { static constexpr bool value = B; };

__device__ __forceinline__ float bf2f(u16 x) {
    union { unsigned int u; float f; } v; v.u = ((unsigned int)x) << 16; return v.f;
}
__device__ __forceinline__ u16 f2bf(float f) {  // RNE
    unsigned int u = __float_as_uint(f);
    return (u16)((u + 0x7fffu + ((u >> 16) & 1u)) >> 16);
}
// pack 2 f32 -> 2 bf16 in one u32 (D.lo = lo, D.hi = hi); no builtin on gfx950
__device__ __forceinline__ unsigned int cvtpk_bf16(float lo, float hi) {
    unsigned int r;
    asm("v_cvt_pk_bf16_f32 %0, %1, %2" : "=v"(r) : "v"(lo), "v"(hi));
    return r;
}

// async global->LDS, 16B per lane; LDS dest is wave-uniform base + lane*16 (m97/m104)
__device__ __forceinline__ void async16(const void* g, void* l) {
    __builtin_amdgcn_global_load_lds(
        (const __attribute__((address_space(1))) unsigned int*)g,
        (__attribute__((address_space(3))) unsigned int*)l, 16, 0, 0);
}

// ---- prep: fused convert_x (z=4..7) + W transposes (z=0..3) ----
__global__ __launch_bounds__(256) void prep(const float* __restrict__ x,
                                            const float* __restrict__ Wq, const float* __restrict__ Wk,
                                            const float* __restrict__ Wv, const float* __restrict__ Wo,
                                            u16* __restrict__ xb, u16* __restrict__ Wqkvt, u16* __restrict__ Wot) {
    __shared__ u16 tile[32][33];
    const int z = blockIdx.z;
    const int tx = threadIdx.x, ty = threadIdx.y;
    if (z >= 4) {  // convert_x path: slice (z-4), 1024 blocks x 256 thr x 4 floats
        const int t = ty * 32 + tx;
        const size_t bid = (size_t)(z - 4) * 1024 + blockIdx.y * 32 + blockIdx.x;
        const size_t i = (bid * 256 + t) * 4;
        float4 v = *(const float4*)&x[i];
        shortx4 h;
        h[0] = (short)f2bf(v.x); h[1] = (short)f2bf(v.y);
        h[2] = (short)f2bf(v.z); h[3] = (short)f2bf(v.w);
        *(shortx4*)&xb[i] = h;
        return;
    }
    const float* W = (z == 0) ? Wq : (z == 1) ? Wk : (z == 2) ? Wv : Wo;
    u16* dst = (z == 3) ? Wot : (Wqkvt + (size_t)z * D_ * D_);
    const int n0 = blockIdx.x * 32, k0 = blockIdx.y * 32;
#pragma unroll
    for (int r = 0; r < 4; ++r) {
        int k = ty + r * 8;
        tile[k][tx] = f2bf(W[(size_t)(k0 + k) * D_ + n0 + tx]);
    }
    __syncthreads();
#pragma unroll
    for (int r = 0; r < 4; ++r) {
        int n = ty + r * 8;
        dst[(size_t)(n0 + n) * D_ + k0 + tx] = tile[tx][n];
    }
}

// ------- Vt[bh][d][s] with sigma key-permutation within each 64-key block -------
// Position p holds original key sigma(p) = 32*(p>>5) + 16*((p>>2)&1) + 4*((p>>3)&3) + (p&3).
// Co-designed with attn's SWAPPED QK^T (P stays in registers). Kept as a separate
// kernel — fusing into the GEMM epilogue (R6) polluted L2 (+15us on the gemm).
__global__ __launch_bounds__(256) void transpose_headV(const u16* __restrict__ QKV, u16* __restrict__ Vt) {
    __shared__ u16 tile[64 * 65];
    const int t = threadIdx.x;
    const int bh = blockIdx.y, b = bh >> 4, h = bh & 15;
    const int s0 = blockIdx.x << 6;
#pragma unroll
    for (int i = 0; i < 16; ++i) {
        int idx = t + (i << 8);
        int s = idx >> 6, d = idx & 63;
        tile[s * 65 + d] = QKV[(size_t)(b * S_ + s0 + s) * DQKV_ + 2048 + h * DH_ + d];
    }
    __syncthreads();
#pragma unroll
    for (int i = 0; i < 16; ++i) {
        int idx = t + (i << 8);
        int d = idx >> 6, p = idx & 63;
        int sk = ((p >> 5) << 5) | (((p >> 2) & 1) << 4) | (((p >> 3) & 3) << 2) | (p & 3);
        Vt[((size_t)bh * DH_ + d) * S_ + s0 + p] = tile[sk * 65 + d];
    }
}

// ------- C[M,N] = A[M,K] @ Bt[N,K]^T + bias; bf16 in, fp32 acc -------
// BMxBN tile, BK=32, 4 waves in 2x2 grid.
// R9: TRIPLE-buffered async-DMA, prefetch distance 2, COUNTED vmcnt (T4), with
// the count now PER-TEMPLATE-INSTANCE: LPT = BM/64 + BN/64 DMAs/wave/tile.
// R8's residual race: it hard-coded vmcnt(4), but the 64x128 out-gemm has LPT=3
// (6 outstanding at the boundary) -> vmcnt(4) left 1 of tile kk's loads
// un-retired -> intermittent stale ds_read in the FINAL-output gemm. Correct
// steady wait = vmcnt(LPT): retires all of tile kk, keeps tile kk+1 in flight.
// The counted wait + s_barrier stay ONE indivisible asm block with "memory"
// clobber (the R8 fix): raw s_barrier has no IR-level memory ordering, so a
// split form lets LLVM hoist ds_reads above the barrier (R7's failure).
// LDS 3x16KB(BM=128)=48KB -> 3 blocks/CU (= the average already resident).
// Kept from R3: bijective XCD swizzle; LDS-staged coalesced bf16 epilogue.
template <int BM, int BN, bool OUTF32>
__global__ __launch_bounds__(256) void gemm_bt(const u16* __restrict__ A, const u16* __restrict__ Bt,
                                               const float* __restrict__ b0, const float* __restrict__ b1,
                                               const float* __restrict__ b2, void* __restrict__ Cp,
                                               int M, int N, int Kd) {
    constexpr int FI = BM / 32, FJ = BN / 32;
    constexpr int LPT = BM / 64 + BN / 64;  // async16 per wave per K-tile
    static_assert(LPT == 3 || LPT == 4, "vmcnt immediate must match LPT");
    __shared__ __align__(16) u16 smem[3][(BM + BN) * 32];  // [buf][A-tile | B-tile]
    const int t = threadIdx.x;

    // XCD-aware bijective swizzle (nwg % 8 == 0 for both launches: 768, 512)
    const int nwg = gridDim.x * gridDim.y;
    int fid = blockIdx.y * gridDim.x + blockIdx.x;
    if ((nwg & 7) == 0) fid = (fid & 7) * (nwg >> 3) + (fid >> 3);
    const int bx = fid % gridDim.x, by = fid / gridDim.x;
    const int m0 = by * BM, n0 = bx * BN;

    const int w = t >> 6, lane = t & 63;
    const int lr = lane & 15, lg = lane >> 4;
    const int wm = (w >> 1) * (BM / 2), wn = (w & 1) * (BN / 2);
    const int srow = lane >> 2, scol = (lane & 3) << 3;  // lane -> (row-in-16, k8)
    floatx4 acc[FI][FJ] = {};

    auto stage = [&](int buf, int k0) {
        u16* As = &smem[buf][0];
        u16* Bs = &smem[buf][BM * 32];
#pragma unroll
        for (int c = 0; c < BM / 64; ++c) {  // one wave-inst stages 16 rows x 64B = 1KB
            int rbase = (w * (BM / 64) + c) * 16;
            async16(&A[(size_t)(m0 + rbase + srow) * Kd + k0 + scol], &As[rbase * 32]);
        }
#pragma unroll
        for (int c = 0; c < BN / 64; ++c) {
            int rbase = (w * (BN / 64) + c) * 16;
            async16(&Bt[(size_t)(n0 + rbase + srow) * Kd + k0 + scol], &Bs[rbase * 32]);
        }
    };

    const int nk = Kd / 32;
    stage(0, 0);       // prologue: tiles 0,1 in flight
    stage(1, 32);
    for (int kk = 0; kk < nk; ++kk) {
        const int cur = kk % 3;
        // ONE asm unit: counted wait + barrier ("memory" clobber = nothing
        // crosses it either direction). N = LPT keeps tile kk+1 in flight.
        if (kk + 1 < nk) {
            if constexpr (LPT == 4) asm volatile("s_waitcnt vmcnt(4)\n\ts_barrier" ::: "memory");
            else                    asm volatile("s_waitcnt vmcnt(3)\n\ts_barrier" ::: "memory");
        } else {
            asm volatile("s_waitcnt vmcnt(0)\n\ts_barrier" ::: "memory");
        }
        if (kk + 2 < nk) stage((kk + 2) % 3, (kk + 2) * 32);  // deep prefetch, stays in flight
        const u16* As = &smem[cur][0];
        const u16* Bs = &smem[cur][BM * 32];

        short8 af[FI], bfr[FJ];
#pragma unroll
        for (int i = 0; i < FI; ++i) af[i]  = *(const short8*)&As[(wm + i * 16 + lr) * 32 + lg * 8];
#pragma unroll
        for (int j = 0; j < FJ; ++j) bfr[j] = *(const short8*)&Bs[(wn + j * 16 + lr) * 32 + lg * 8];
#pragma unroll
        for (int i = 0; i < FI; ++i)
#pragma unroll
            for (int j = 0; j < FJ; ++j)
                acc[i][j] = __builtin_amdgcn_mfma_f32_16x16x32_bf16(af[i], bfr[j], acc[i][j], 0, 0, 0);
    }

    if (!OUTF32) {
        // --- LDS-staged coalesced bf16 epilogue ---
        __syncthreads();  // all frag reads done; smem reusable as C-staging
        u16* Cs = &smem[0][0];  // BM*BN u16 (=32KB for 128x128) fits in 48KB smem
#pragma unroll
        for (int j = 0; j < FJ; ++j) {
            int c = wn + j * 16 + lr;
            int col = n0 + c;
            const float* bp = (col < 1024) ? b0 : (col < 2048) ? b1 : b2;
            float bv = bp[col & 1023];
#pragma unroll
            for (int i = 0; i < FI; ++i)
#pragma unroll
                for (int ii = 0; ii < 4; ++ii) {
                    int r = wm + i * 16 + lg * 4 + ii;
                    // XOR-swizzle col bits 3..6 by (r&15): write-side <=2-way banked
                    Cs[r * BN + (c ^ ((r & 15) << 3))] = f2bf(acc[i][j][ii] + bv);
                }
        }
        __syncthreads();
        constexpr int CPR = BN / 8;               // 16B chunks per row
        constexpr int ITER = BM * CPR / 256;      // chunks per thread
#pragma unroll
        for (int it = 0; it < ITER; ++it) {
            int g = it * 256 + t;
            int r = g / CPR, cc = g % CPR;
            short8 vv = *(const short8*)&Cs[r * BN + ((cc * 8) ^ ((r & 15) << 3))];
            *(short8*)((u16*)Cp + (size_t)(m0 + r) * N + n0 + cc * 8) = vv;
        }
    } else {
        // fp32 path: 16 lanes x 4B = 64B per row-group, already full-sector coalesced
#pragma unroll
        for (int j = 0; j < FJ; ++j) {
            int col = n0 + wn + j * 16 + lr;
            const float* bp = (col < 1024) ? b0 : (col < 2048) ? b1 : b2;
            float bv = bp[col & 1023];
#pragma unroll
            for (int i = 0; i < FI; ++i) {
                int rb = m0 + wm + i * 16 + lg * 4;
#pragma unroll
                for (int ii = 0; ii < 4; ++ii)
                    ((float*)Cp)[(size_t)(rb + ii) * N + col] = acc[i][j][ii] + bv;
            }
        }
    }
}

// ---------------- MFMA flash attention: swapped-QK^T, P in-register, split-KQ waves ----------------
// grid (bh=32, y=32). 256-thr blocks. Waves split 2x2 over (q-half wq, key-half wk);
// K/V staging, XOR swizzle, sigma-permuted V, in-register P (verified R3/R5 paths).
// Two key-halves merge once at the end via 16KB LDS reduction. Balanced qt remap.
__global__ __launch_bounds__(256, 4) void attn_mfma(const u16* __restrict__ QKV, const u16* __restrict__ Vt,
                                                    u16* __restrict__ O) {
    __shared__ __align__(16) u16 KsA[2][64 * 64];  // [key][d], packed 128B rows, XOR-swizzled chunks
    __shared__ __align__(16) u16 VsA[2][64 * 64];  // [d][key-permuted]
    const int t = threadIdx.x, w = t >> 6, lane = t & 63;
    const int lr = lane & 15, lg = lane >> 4;
    const int wq = w & 1, wk = w >> 1;
    const int bh = blockIdx.x, b = bh >> 4, h = bh & 15;
    const int ya = blockIdx.y & 7, yb = blockIdx.y >> 3;
    const int a4 = (ya + 4) & 7;
    const int cq = (yb == 0) ? ya : (yb == 1) ? (7 - ya) : (yb == 2) ? a4 : (7 - a4);
    const int qt = (yb << 3) + cq;
    const int q0 = qt << 6;
    const float cs = 0.18033688f;  // (1/sqrt(64)) * log2(e)

    const u16* Kb  = QKV + (size_t)b * S_ * DQKV_ + 1024 + h * DH_;  // row stride DQKV_
    const u16* Vtb = Vt + (size_t)bh * DH_ * S_;                     // row stride S_

    const int rb8 = lane >> 3;               // row within 8-row staging group
    const int cc = ((lane & 7) ^ rb8) << 3;  // swizzled source chunk (u16 offset)
    const int swz = lr & 7;                  // frag-read swizzle key (= row&7)

    short8 qf[2][2];  // Q frags (B-operand): [qs][ks] rows q0+wq*32+qs*16+lr, d-chunk ks*32+lg*8
#pragma unroll
    for (int qs = 0; qs < 2; ++qs)
#pragma unroll
        for (int ks = 0; ks < 2; ++ks)
            qf[qs][ks] = *(const short8*)&QKV[(size_t)(b * S_ + q0 + wq * 32 + qs * 16 + lr) * DQKV_ +
                                              h * DH_ + ks * 32 + lg * 8];

    floatx4 of[2][4] = {};   // O-partial [qs][ttd]: row(q16)=lg*4+ii, col(d)=ttd*16+lr
    float lsum[2] = {0.f, 0.f};  // per-lane row-sum partial, per q-subblock

    auto stage = [&](int buf, int kbase) {
        u16* Kd = &KsA[buf][w * 512];  // wave w stages rows w*8.. and 32+w*8.. (K and V)
        u16* Vd = &VsA[buf][w * 512];
        async16(&Kb[(size_t)(kbase + w * 8 + rb8) * DQKV_ + cc], Kd);
        async16(&Kb[(size_t)(kbase + 32 + w * 8 + rb8) * DQKV_ + cc], Kd + 2048);
        async16(&Vtb[(size_t)(w * 8 + rb8) * S_ + kbase + cc], Vd);
        async16(&Vtb[(size_t)(32 + w * 8 + rb8) * S_ + kbase + cc], Vd + 2048);
    };

    stage(0, 0);  // prologue: DMA tile 0 into buffer 0

    auto body = [&](int kb, auto diagc) {
        constexpr bool DIAG = decltype(diagc)::value;
        const int cur = kb & 1;
        __syncthreads();  // implicit vmcnt(0) drain: buffer `cur` is ready
        if (kb < qt) stage(cur ^ 1, (kb + 1) << 6);  // prefetch overlaps compute below
        const u16* Kc = KsA[cur];
        const u16* Vc = VsA[cur];

        // S^T = K @ Q^T on this wave's quadrant: sf[qs][tt]
        floatx4 sf[2][2] = {};
        __builtin_amdgcn_s_setprio(1);
#pragma unroll
        for (int ks = 0; ks < 2; ++ks)
#pragma unroll
            for (int tt = 0; tt < 2; ++tt) {
                short8 kf = *(const short8*)&Kc[(wk * 32 + tt * 16 + lr) * 64 + ((((ks << 2) + lg) ^ swz) << 3)];
                sf[0][tt] = __builtin_amdgcn_mfma_f32_16x16x32_bf16(kf, qf[0][ks], sf[0][tt], 0, 0, 0);
                sf[1][tt] = __builtin_amdgcn_mfma_f32_16x16x32_bf16(kf, qf[1][ks], sf[1][tt], 0, 0, 0);
            }
        __builtin_amdgcn_s_setprio(0);

        // no-max softmax, per-lane: e = 2^(s*cs); masked -> 0 (diag tile only)
        float ev[2][2][4];
#pragma unroll
        for (int qs = 0; qs < 2; ++qs)
#pragma unroll
            for (int tt = 0; tt < 2; ++tt) {
                float s0;
#pragma unroll
                for (int ii = 0; ii < 4; ++ii) {
                    float e = EXP2F(sf[qs][tt][ii] * cs);
                    if (DIAG && (wk * 32 + tt * 16 + lg * 4 + ii > wq * 32 + qs * 16 + lr)) e = 0.f;
                    ev[qs][tt][ii] = e;
                    s0 = (ii == 0) ? e : s0 + e;
                }
                lsum[qs] += s0;
            }

        // PV partial (positions ks=wk only): A = lane's own e's (sigma alignment),
        // B = V rows, chunk (wk,lg).
        short8 vfr[4];
#pragma unroll
        for (int ttd = 0; ttd < 4; ++ttd)
            vfr[ttd] = *(const short8*)&Vc[(ttd * 16 + lr) * 64 + ((((wk << 2) + lg) ^ swz) << 3)];
        __builtin_amdgcn_s_setprio(1);
#pragma unroll
        for (int qs = 0; qs < 2; ++qs) {
            union { short8 s; unsigned int u[4]; } pk;
            pk.u[0] = cvtpk_bf16(ev[qs][0][0], ev[qs][0][1]);
            pk.u[1] = cvtpk_bf16(ev[qs][0][2], ev[qs][0][3]);
            pk.u[2] = cvtpk_bf16(ev[qs][1][0], ev[qs][1][1]);
            pk.u[3] = cvtpk_bf16(ev[qs][1][2], ev[qs][1][3]);
#pragma unroll
            for (int ttd = 0; ttd < 4; ++ttd)
                of[qs][ttd] = __builtin_amdgcn_mfma_f32_16x16x32_bf16(pk.s, vfr[ttd], of[qs][ttd], 0, 0, 0);
        }
        __builtin_amdgcn_s_setprio(0);
    };

    for (int kb = 0; kb < qt; ++kb) body(kb, BoolC<false>{});  // full tiles: no mask code
    body(qt, BoolC<true>{});                                   // diagonal tile: masked

    // ---- merge the two key-halves (once): wk=1 waves publish, wk=0 waves reduce ----
    __syncthreads();  // all waves done with K/V LDS; reuse as merge buffers
    float* mb = (float*)&KsA[0][0];
    float* lb = (float*)&VsA[0][0];
    if (wk == 1) {
        float* mw = mb + wq * 2048;
#pragma unroll
        for (int qs = 0; qs < 2; ++qs)
#pragma unroll
            for (int ttd = 0; ttd < 4; ++ttd)
                *(floatx4*)&mw[(qs * 4 + ttd) * 256 + lane * 4] = of[qs][ttd];
        lb[wq * 128 + lane * 2 + 0] = lsum[0];
        lb[wq * 128 + lane * 2 + 1] = lsum[1];
    }
    __syncthreads();
    if (wk == 0) {
        float* mw = mb + wq * 2048;
#pragma unroll
        for (int qs = 0; qs < 2; ++qs)
#pragma unroll
            for (int ttd = 0; ttd < 4; ++ttd)
                of[qs][ttd] += *(const floatx4*)&mw[(qs * 4 + ttd) * 256 + lane * 4];
        lsum[0] += lb[wq * 128 + lane * 2 + 0];
        lsum[1] += lb[wq * 128 + lane * 2 + 1];

        float rv[2][4];
#pragma unroll
        for (int qs = 0; qs < 2; ++qs) {
            float s = lsum[qs];
            s += __shfl_xor(s, 16);
            s += __shfl_xor(s, 32);
            float rinv = 1.f / s;
#pragma unroll
            for (int ii = 0; ii < 4; ++ii)
                rv[qs][ii] = __shfl(rinv, (lane & 48) | (lg * 4 + ii));
        }
#pragma unroll
        for (int qs = 0; qs < 2; ++qs)
#pragma unroll
            for (int ttd = 0; ttd < 4; ++ttd)
#pragma unroll
                for (int ii = 0; ii < 4; ++ii)
                    O[(size_t)(b * S_ + q0 + wq * 32 + qs * 16 + lg * 4 + ii) * D_ + h * DH_ + ttd * 16 + lr] =
                        f2bf(of[qs][ttd][ii] * rv[qs][ii]);
    }
}

extern "C" void kernel_launch(void* const* d_in, const int* in_sizes, int n_in,
                              void* d_out, int out_size, void* d_ws, size_t ws_size,
                              hipStream_t stream) {
    (void)in_sizes; (void)n_in; (void)out_size; (void)ws_size;
    const float* x  = (const float*)d_in[0];
    const float* Wq = (const float*)d_in[1];
    const float* bq = (const float*)d_in[2];
    const float* Wk = (const float*)d_in[3];
    const float* bk = (const float*)d_in[4];
    const float* Wv = (const float*)d_in[5];
    const float* bv = (const float*)d_in[6];
    const float* Wo = (const float*)d_in[7];
    const float* bo = (const float*)d_in[8];

    // ws layout (u16 elems), 48 MB total:
    //   [0,3M) WqkvT  [3M,4M) WoT  [4M,16M) QKV  [16M,20M) Vt  [20M,24M) xbf -> reused as Am
    u16* ws    = (u16*)d_ws;
    u16* WqkvT = ws;
    u16* WoT   = ws + (size_t)3 * (1 << 20);
    u16* QKV   = ws + (size_t)4 * (1 << 20);
    u16* Vtm   = ws + (size_t)16 * (1 << 20);
    u16* xbf   = ws + (size_t)20 * (1 << 20);
    u16* Am    = ws + (size_t)20 * (1 << 20);

    // fused convert + W transposes
    prep<<<dim3(32, 32, 8), dim3(32, 8), 0, stream>>>(x, Wq, Wk, Wv, Wo, xbf, WqkvT, WoT);

    // QKV = xbf @ WqkvT^T + [bq|bk|bv]  (M=4096, N=3072)
    gemm_bt<128, 128, false><<<dim3(DQKV_ / 128, 4096 / 128), 256, 0, stream>>>(
        xbf, WqkvT, bq, bk, bv, QKV, 4096, DQKV_, 1024);

    transpose_headV<<<dim3(32, 32), 256, 0, stream>>>(QKV, Vtm);

    attn_mfma<<<dim3(32, 32), 256, 0, stream>>>(QKV, Vtm, Am);

    // out = Am @ WoT^T + bo  (M=4096, N=1024), fp32 out
    gemm_bt<64, 128, true><<<dim3(1024 / 128, 4096 / 64), 256, 0, stream>>>(
        Am, WoT, bo, bo, bo, d_out, 4096, 1024, 1024);
}